// Round 1
// baseline (318.681 us; speedup 1.0000x reference)
//
#include <hip/hip_runtime.h>

// B=16, H=256, W=256, CIN=COUT=32, kept modes: kh in {0..15,-16..-1}, kw in 0..16
#define NB 16
#define NH 256
#define EM1 17
#define TWO_PI 6.283185307179586f

typedef short short8 __attribute__((ext_vector_type(8)));
typedef float floatx4 __attribute__((ext_vector_type(4)));

__device__ __forceinline__ unsigned f2b(float x){ union{float f; unsigned u;} v; v.f=x; return v.u; }
__device__ __forceinline__ float b2f(unsigned u){ union{float f; unsigned u;} v; v.u=u; return v.f; }

__device__ __forceinline__ void cmul_upd(float& tr, float& ti, float wr, float wi) {
    float nr = tr * wr - ti * wi;
    float ni = tr * wi + ti * wr;
    tr = nr; ti = ni;
}

// ---------------- K0: weight transpose ----------------
// src: w1r/w1i/w2r/w2i each (CIN=32, COUT=32, 16, 17):  ((i*32+o)*16+h)*17+kw
// dst: wt[kw][m][i][o] float2 (re,im), m<16 -> w1 h=m, m>=16 -> w2 h=m-16
// grid 128 blocks: (i, o-quarter). Coalesced reads (contiguous 2176-float run
// per (i, o-range)), coalesced 64B-run writes.
__global__ __launch_bounds__(256) void k0_wt(const float* __restrict__ w1r,
                                             const float* __restrict__ w1i,
                                             const float* __restrict__ w2r,
                                             const float* __restrict__ w2i,
                                             float2* __restrict__ wt) {
    __shared__ __align__(16) float l1r[2176], l1i[2176], l2r[2176], l2i[2176];
    const int t = threadIdx.x;
    const int i = blockIdx.x >> 2;       // 0..31
    const int oq = blockIdx.x & 3;       // 0..3 (o base = oq*8)
    const size_t off = (size_t)(i * 32 + oq * 8) * 272;   // 8 (i,o)-rows of 272
    for (int u = t; u < 544; u += 256) {                  // 2176 floats = 544 f4
        ((float4*)l1r)[u] = ((const float4*)(w1r + off))[u];
        ((float4*)l1i)[u] = ((const float4*)(w1i + off))[u];
        ((float4*)l2r)[u] = ((const float4*)(w2r + off))[u];
        ((float4*)l2i)[u] = ((const float4*)(w2i + off))[u];
    }
    __syncthreads();
    for (int v = t; v < 4352; v += 256) {   // 17 kw * 32 m * 8 o
        const int kw = v >> 8;              // 0..16
        const int rem = v & 255;
        const int m = rem >> 3, o8 = rem & 7;
        const int h = m & 15;
        const int lidx = o8 * 272 + h * 17 + kw;
        const float vr = (m < 16) ? l1r[lidx] : l2r[lidx];
        const float vi = (m < 16) ? l1i[lidx] : l2i[lidx];
        wt[((size_t)(kw * 32 + m) * 32 + i) * 32 + oq * 8 + o8] = make_float2(vr, vi);
    }
}

// ---------------- K1: forward W-DFT via MFMA bf16x2 (unchanged) ----------------
// Per (b,y)-row GEMM: D[i][n] = sum_x A[i][x] * B[x][n],  M=32, K=256, N=34
// Xw layout (float view): [b][kw][y][i*2+reim]
__global__ __launch_bounds__(256, 2) void k1_fwdW_mfma(const float* __restrict__ x,
                                                       float* __restrict__ Xw) {
    __shared__ __align__(16) short alds[16384];
    const int t = threadIdx.x;
    const int w = t >> 6;
    const int l = t & 63;
    const int mt = w & 1;
    const int g  = w >> 1;
    const int nn = (g == 0) ? 2 : 1;

    short8 Bh[2][8], Bl[2][8];
    const float sc = 1.0f / 65536.0f;
    #pragma unroll
    for (int u = 0; u < 2; ++u) {
        const int nt  = (g == 0) ? u : 2;
        const int n   = nt * 16 + (l & 15);
        const int kwv = n >> 1;
        const int par = n & 1;
        const bool live = (u < nn) && (n < 34);
        const float dth = (TWO_PI / 256.f) * (float)kwv;
        #pragma unroll
        for (int ks = 0; ks < 8; ++ks) {
            const int k0 = ks * 32 + (l >> 4) * 8;
            float s, c; sincosf(dth * (float)k0, &s, &c);
            float sd, cd; sincosf(dth, &sd, &cd);
            short8 vh, vl;
            #pragma unroll
            for (int j = 0; j < 8; ++j) {
                float v = live ? ((par ? -s : c) * sc) : 0.f;
                unsigned ub = f2b(v);
                short h16 = (short)(ub >> 16);
                float rres = v - b2f(ub & 0xFFFF0000u);
                short l16 = (short)(f2b(rres) >> 16);
                vh[j] = h16; vl[j] = l16;
                float ncv = c * cd - s * sd, nsv = c * sd + s * cd;
                c = ncv; s = nsv;
            }
            Bh[u][ks] = vh; Bl[u][ks] = vl;
        }
    }

    const int i   = t & 31;
    const int slot = t >> 5;
    const int i15 = i & 15, imt = i >> 4;
    const int i15l = l & 15, ql = l >> 4;

    for (int ir = 0; ir < 8; ++ir) {
        const int row = blockIdx.x * 8 + ir;
        const int b = row >> 8, y = row & 255;
        __syncthreads();
        {
            const float* rp = x + (size_t)row * 8192;
            unsigned* al32 = (unsigned*)alds;
            #pragma unroll
            for (int c = 0; c < 16; ++c) {
                const int xp = slot + (c << 3);
                float v0 = rp[xp * 64 + i];
                float v1 = rp[xp * 64 + 32 + i];
                unsigned u0 = f2b(v0), u1 = f2b(v1);
                unsigned hi = (u0 >> 16) | (u1 & 0xFFFF0000u);
                float r0 = v0 - b2f(u0 & 0xFFFF0000u);
                float r1 = v1 - b2f(u1 & 0xFFFF0000u);
                unsigned lo = (f2b(r0) >> 16) | (f2b(r1) & 0xFFFF0000u);
                const int ks = xp >> 4, q = (xp & 15) >> 2, dw = xp & 3;
                const int base = (ks * 2 + imt) * 256 + (q * 16 + i15) * 4 + dw;
                al32[base] = hi;
                al32[base + 16 * 256] = lo;
            }
        }
        __syncthreads();
        floatx4 acc0 = {0.f, 0.f, 0.f, 0.f};
        floatx4 acc1 = {0.f, 0.f, 0.f, 0.f};
        #pragma unroll
        for (int ks = 0; ks < 8; ++ks) {
            const short8 ah = *(const short8*)(alds + ((ks * 2 + mt) * 512) + l * 8);
            const short8 al = *(const short8*)(alds + ((16 + ks * 2 + mt) * 512) + l * 8);
            acc0 = __builtin_amdgcn_mfma_f32_16x16x32_bf16(ah, Bh[0][ks], acc0, 0, 0, 0);
            acc0 = __builtin_amdgcn_mfma_f32_16x16x32_bf16(ah, Bl[0][ks], acc0, 0, 0, 0);
            acc0 = __builtin_amdgcn_mfma_f32_16x16x32_bf16(al, Bh[0][ks], acc0, 0, 0, 0);
            if (nn == 2) {
                acc1 = __builtin_amdgcn_mfma_f32_16x16x32_bf16(ah, Bh[1][ks], acc1, 0, 0, 0);
                acc1 = __builtin_amdgcn_mfma_f32_16x16x32_bf16(ah, Bl[1][ks], acc1, 0, 0, 0);
                acc1 = __builtin_amdgcn_mfma_f32_16x16x32_bf16(al, Bh[1][ks], acc1, 0, 0, 0);
            }
        }
        #pragma unroll
        for (int u = 0; u < 2; ++u) {
            if (u >= nn) break;
            const int nt = (g == 0) ? u : 2;
            const int n = nt * 16 + i15l;
            if (n < 34) {
                const int kwv = n >> 1, par = n & 1;
                float* dst = Xw + (((size_t)(b * 17 + kwv) * 256 + y) * 64) + par;
                const floatx4 a = (u == 0) ? acc0 : acc1;
                #pragma unroll
                for (int r = 0; r < 4; ++r) {
                    const int ii = mt * 16 + ql * 4 + r;
                    dst[ii * 2] = a[r];
                }
            }
        }
    }
}

// ---------------- KMID: fused forward H-DFT + mode mix + inverse H-DFT ----------------
// One block per (b,kw) slab, 512 threads (8 waves). All intermediates in LDS.
//   phase1 (=old K2): xhat[m][i] = sum_y Xw[b,kw,y,i] * e^{-2pi i kh y/256}
//   phase2 (=old K3): osl[m][o]  = sum_i xhat[m][i] * w[m][i][o]   (wt pre-transposed)
//   phase3 (=old K4): T[b,y,kw,o] = sum_m osl[m][o] * e^{+2pi i kh y/256}
// Xw slab staged in two 32KB halves to keep LDS at 48KB.
__global__ __launch_bounds__(512) void kmid(const float2* __restrict__ Xw,
                                            const float2* __restrict__ wt,
                                            float2* __restrict__ T) {
    __shared__ __align__(16) float2 xsh[128 * 32];   // 32 KB [y-half][i]
    __shared__ __align__(16) float2 xhat[32 * 32];   // 8 KB  [m][i]
    __shared__ __align__(16) float2 osl[32 * 32];    // 8 KB  [m][o]
    const int t = threadIdx.x;
    const int bk = blockIdx.x;
    const int b = bk / 17, kw = bk - b * 17;
    const float4* src4 = (const float4*)(Xw + (size_t)bk * 8192);

    // ---- phase 1: forward H-DFT (256 y -> 32 kh), per-thread (m, i-pair) ----
    const int m1 = t & 31, ip2 = t >> 5;             // i = ip2*2 + {0,1}
    const int kh = (m1 < 16) ? m1 : m1 - 32;
    float wc, ws; sincosf(-TWO_PI * (float)kh * (1.f / 256.f), &ws, &wc);
    float tr = 1.f, ti = 0.f;
    float a0r = 0.f, a0i = 0.f, a1r = 0.f, a1i = 0.f;
    const float* xp = (const float*)xsh + ip2 * 4;
    for (int half = 0; half < 2; ++half) {
        __syncthreads();                              // protect prev contents
        #pragma unroll
        for (int q = 0; q < 4; ++q) {                 // stage 2048 float4 = 32KB
            int v = q * 512 + t;
            ((float4*)xsh)[v] = src4[half * 2048 + v];
        }
        __syncthreads();
        #pragma unroll 8
        for (int yy = 0; yy < 128; ++yy) {
            float4 v = *(const float4*)(xp + yy * 64);
            a0r = fmaf(v.x, tr, a0r); a0r = fmaf(-v.y, ti, a0r);
            a0i = fmaf(v.x, ti, a0i); a0i = fmaf(v.y, tr, a0i);
            a1r = fmaf(v.z, tr, a1r); a1r = fmaf(-v.w, ti, a1r);
            a1i = fmaf(v.z, ti, a1i); a1i = fmaf(v.w, tr, a1i);
            cmul_upd(tr, ti, wc, ws);
        }
    }
    *(float4*)(xhat + m1 * 32 + ip2 * 2) = make_float4(a0r, a0i, a1r, a1i);
    __syncthreads();

    // ---- phase 2: mode mix (32 i -> 32 o), per-thread (m, o-pair) ----
    {
        const int o2 = t & 15, m = t >> 4;
        const float4* wp = (const float4*)wt + ((size_t)(kw * 32 + m) * 32) * 16 + o2;
        float ar0 = 0.f, ai0 = 0.f, ar1 = 0.f, ai1 = 0.f;
        #pragma unroll 8
        for (int ii = 0; ii < 32; ++ii) {
            float2 xv = xhat[m * 32 + ii];
            float4 wv = wp[(size_t)ii * 16];          // (w[o].re, w[o].im, w[o+1].re, w[o+1].im)
            ar0 = fmaf(xv.x, wv.x, ar0); ar0 = fmaf(-xv.y, wv.y, ar0);
            ai0 = fmaf(xv.x, wv.y, ai0); ai0 = fmaf(xv.y, wv.x, ai0);
            ar1 = fmaf(xv.x, wv.z, ar1); ar1 = fmaf(-xv.y, wv.w, ar1);
            ai1 = fmaf(xv.x, wv.w, ai1); ai1 = fmaf(xv.y, wv.z, ai1);
        }
        *(float4*)(osl + m * 32 + o2 * 2) = make_float4(ar0, ai0, ar1, ai1);
    }
    __syncthreads();

    // ---- phase 3: inverse H-DFT (32 kh -> 256 y), per-thread (y, o-half) ----
    {
        const int y = t & 255, oh = t >> 8;
        float uc, us; sincosf(TWO_PI * (float)y * (1.f / 256.f), &us, &uc);
        float tr2 = 1.f, ti2 = 0.f;
        float ar[16], ai[16];
        #pragma unroll
        for (int o = 0; o < 16; ++o) { ar[o] = 0.f; ai[o] = 0.f; }
        for (int m = 0; m < 32; ++m) {
            if (m == 16) ti2 = -ti2;                  // kh jumps +16 -> -16
            #pragma unroll
            for (int o2 = 0; o2 < 8; ++o2) {
                float4 v = *(const float4*)((const float*)osl + m * 64 + oh * 32 + o2 * 4);
                int o = o2 * 2;
                ar[o]   = fmaf(v.x, tr2, ar[o]);   ar[o]   = fmaf(-v.y, ti2, ar[o]);
                ai[o]   = fmaf(v.x, ti2, ai[o]);   ai[o]   = fmaf(v.y, tr2, ai[o]);
                ar[o+1] = fmaf(v.z, tr2, ar[o+1]); ar[o+1] = fmaf(-v.w, ti2, ar[o+1]);
                ai[o+1] = fmaf(v.z, ti2, ai[o+1]); ai[o+1] = fmaf(v.w, tr2, ai[o+1]);
            }
            cmul_upd(tr2, ti2, uc, us);
        }
        float2* dst = T + ((size_t)(b * 256 + y) * 17 + kw) * 32 + oh * 16;
        #pragma unroll
        for (int o2 = 0; o2 < 8; ++o2)
            *(float4*)(dst + o2 * 2) =
                make_float4(ar[o2*2], ai[o2*2], ar[o2*2+1], ai[o2*2+1]);
    }
}

// ---------------- K5: inverse W reconstruction + bias (unchanged) ----------------
__global__ __launch_bounds__(256) void k5_invW(const float2* __restrict__ T,
                                               const float* __restrict__ bias,
                                               float* __restrict__ out) {
    __shared__ __align__(16) float2 tl[544];
    __shared__ float bl[32];
    const int t = threadIdx.x;
    const int blk = blockIdx.x;
    const float4* src4 = (const float4*)(T + (size_t)blk * 544);
    for (int u = t; u < 272; u += 256) ((float4*)tl)[u] = src4[u];
    if (t < 32) bl[t] = bias[t];
    __syncthreads();
    const int o8 = t & 3, xq = t >> 2;
    float c0, s0; sincosf(TWO_PI * (float)(xq * 4) * (1.f / 256.f), &s0, &c0);
    const float CC = 0.99969881869620422f, SS = 0.02454122852291229f;
    float ur[4], ui[4];
    ur[0] = c0; ui[0] = s0;
    #pragma unroll
    for (int k = 1; k < 4; ++k) {
        ur[k] = ur[k-1] * CC - ui[k-1] * SS;
        ui[k] = ur[k-1] * SS + ui[k-1] * CC;
    }
    float tr_[4], ti_[4];
    #pragma unroll
    for (int k = 0; k < 4; ++k) { tr_[k] = ur[k]; ti_[k] = ui[k]; }
    float acc[4][8];
    #pragma unroll
    for (int k = 0; k < 4; ++k)
        #pragma unroll
        for (int o = 0; o < 8; ++o) acc[k][o] = 0.f;
    #pragma unroll 4
    for (int kw = 1; kw < 17; ++kw) {
        #pragma unroll
        for (int o2 = 0; o2 < 4; ++o2) {
            float4 v = *(const float4*)((const float*)tl + kw * 64 + o8 * 16 + o2 * 4);
            #pragma unroll
            for (int k = 0; k < 4; ++k) {
                acc[k][o2*2]   = fmaf(v.x, tr_[k], acc[k][o2*2]);
                acc[k][o2*2]   = fmaf(-v.y, ti_[k], acc[k][o2*2]);
                acc[k][o2*2+1] = fmaf(v.z, tr_[k], acc[k][o2*2+1]);
                acc[k][o2*2+1] = fmaf(-v.w, ti_[k], acc[k][o2*2+1]);
            }
        }
        #pragma unroll
        for (int k = 0; k < 4; ++k) cmul_upd(tr_[k], ti_[k], ur[k], ui[k]);
    }
    float base[8];
    #pragma unroll
    for (int o = 0; o < 8; ++o) {
        int og = o8 * 8 + o;
        base[o] = tl[og].x + bl[og];
    }
    float* orow = out + (size_t)blk * 8192;
    #pragma unroll
    for (int k = 0; k < 4; ++k) {
        int xx = xq * 4 + k;
        float res[8];
        #pragma unroll
        for (int o = 0; o < 8; ++o) res[o] = fmaf(2.f, acc[k][o], base[o]);
        float* dst = orow + xx * 32 + o8 * 8;
        *(float4*)(dst)     = make_float4(res[0], res[1], res[2], res[3]);
        *(float4*)(dst + 4) = make_float4(res[4], res[5], res[6], res[7]);
    }
}

extern "C" void kernel_launch(void* const* d_in, const int* in_sizes, int n_in,
                              void* d_out, int out_size, void* d_ws, size_t ws_size,
                              hipStream_t stream) {
    const float* x    = (const float*)d_in[0];
    const float* w1r  = (const float*)d_in[1];
    const float* w1i  = (const float*)d_in[2];
    const float* w2r  = (const float*)d_in[3];
    const float* w2i  = (const float*)d_in[4];
    const float* bias = (const float*)d_in[5];
    float* out = (float*)d_out;

    char* ws = (char*)d_ws;
    // Xw: 16*17*256*32 float2 = 17,825,792 B
    // T : same size (separate — fusion removed the device-wide barrier that
    //     made the old Xw/T alias safe)
    // wt: 17*32*32*32 float2 = 4,456,448 B
    float2* Xw = (float2*)ws;
    float2* T  = (float2*)(ws + 17825792);
    float2* wt = (float2*)(ws + 2 * 17825792);

    k0_wt<<<128, 256, 0, stream>>>(w1r, w1i, w2r, w2i, wt);
    k1_fwdW_mfma<<<512, 256, 0, stream>>>(x, (float*)Xw);
    kmid<<<NB * EM1, 512, 0, stream>>>(Xw, wt, T);
    k5_invW<<<NB * NH, 256, 0, stream>>>(T, bias, out);
}

// Round 2
// 311.542 us; speedup vs baseline: 1.0229x; 1.0229x over previous
//
#include <hip/hip_runtime.h>

// B=16, H=256, W=256, CIN=COUT=32, kept modes: kh in {0..15,-16..-1}, kw in 0..16
#define NB 16
#define NH 256
#define EM1 17
#define TWO_PI 6.283185307179586f

typedef short short8 __attribute__((ext_vector_type(8)));
typedef float floatx4 __attribute__((ext_vector_type(4)));

__device__ __forceinline__ unsigned f2b(float x){ union{float f; unsigned u;} v; v.f=x; return v.u; }
__device__ __forceinline__ float b2f(unsigned u){ union{float f; unsigned u;} v; v.u=u; return v.f; }

__device__ __forceinline__ void cmul_upd(float& tr, float& ti, float wr, float wi) {
    float nr = tr * wr - ti * wi;
    float ni = tr * wi + ti * wr;
    tr = nr; ti = ni;
}

// ---------------- K0: weight transpose (unchanged) ----------------
__global__ __launch_bounds__(256) void k0_wt(const float* __restrict__ w1r,
                                             const float* __restrict__ w1i,
                                             const float* __restrict__ w2r,
                                             const float* __restrict__ w2i,
                                             float2* __restrict__ wt) {
    __shared__ __align__(16) float l1r[2176], l1i[2176], l2r[2176], l2i[2176];
    const int t = threadIdx.x;
    const int i = blockIdx.x >> 2;
    const int oq = blockIdx.x & 3;
    const size_t off = (size_t)(i * 32 + oq * 8) * 272;
    for (int u = t; u < 544; u += 256) {
        ((float4*)l1r)[u] = ((const float4*)(w1r + off))[u];
        ((float4*)l1i)[u] = ((const float4*)(w1i + off))[u];
        ((float4*)l2r)[u] = ((const float4*)(w2r + off))[u];
        ((float4*)l2i)[u] = ((const float4*)(w2i + off))[u];
    }
    __syncthreads();
    for (int v = t; v < 4352; v += 256) {
        const int kw = v >> 8;
        const int rem = v & 255;
        const int m = rem >> 3, o8 = rem & 7;
        const int h = m & 15;
        const int lidx = o8 * 272 + h * 17 + kw;
        const float vr = (m < 16) ? l1r[lidx] : l2r[lidx];
        const float vi = (m < 16) ? l1i[lidx] : l2i[lidx];
        wt[((size_t)(kw * 32 + m) * 32 + i) * 32 + oq * 8 + o8] = make_float2(vr, vi);
    }
}

// ---------------- K5PRE: inverse-W twiddle A-fragments (bf16 hi/lo) ----------------
// A[x][2kw]   = (kw?2:1) * cos(2pi kw x/256)
// A[x][2kw+1] = -(kw?2:1) * sin(2pi kw x/256),  k>=34 -> 0  (K padded to 64)
// Fragment layout (matches verified K1 A-layout): lane l, elem j ->
//   A[mt*16 + (l&15)][ks*32 + (l>>4)*8 + j];  Atab[((mt*2+ks)*2+h)*64 + l]
__global__ __launch_bounds__(256) void k5pre(short8* __restrict__ Atab) {
    const int c = blockIdx.x * 256 + threadIdx.x;    // (mt, ks, l)
    if (c >= 2048) return;
    const int mt = c >> 7, ks = (c >> 6) & 1, l = c & 63;
    const int x = mt * 16 + (l & 15);
    const int kbase = ks * 32 + (l >> 4) * 8;
    short8 vh, vl;
    #pragma unroll
    for (int j = 0; j < 8; ++j) {
        const int k = kbase + j;
        float v = 0.f;
        if (k < 34) {
            const int kw = k >> 1;
            float s, ct; sincosf((TWO_PI / 256.f) * (float)(kw * x), &s, &ct);
            const float sc2 = (kw == 0) ? 1.f : 2.f;
            v = (k & 1) ? (-s * sc2) : (ct * sc2);
        }
        unsigned ub = f2b(v);
        vh[j] = (short)(ub >> 16);
        float r = v - b2f(ub & 0xFFFF0000u);
        vl[j] = (short)(f2b(r) >> 16);
    }
    Atab[((mt * 2 + ks) * 2 + 0) * 64 + l] = vh;
    Atab[((mt * 2 + ks) * 2 + 1) * 64 + l] = vl;
}

// ---------------- K1: forward W-DFT via MFMA bf16x2 (unchanged) ----------------
__global__ __launch_bounds__(256, 2) void k1_fwdW_mfma(const float* __restrict__ x,
                                                       float* __restrict__ Xw) {
    __shared__ __align__(16) short alds[16384];
    const int t = threadIdx.x;
    const int w = t >> 6;
    const int l = t & 63;
    const int mt = w & 1;
    const int g  = w >> 1;
    const int nn = (g == 0) ? 2 : 1;

    short8 Bh[2][8], Bl[2][8];
    const float sc = 1.0f / 65536.0f;
    #pragma unroll
    for (int u = 0; u < 2; ++u) {
        const int nt  = (g == 0) ? u : 2;
        const int n   = nt * 16 + (l & 15);
        const int kwv = n >> 1;
        const int par = n & 1;
        const bool live = (u < nn) && (n < 34);
        const float dth = (TWO_PI / 256.f) * (float)kwv;
        #pragma unroll
        for (int ks = 0; ks < 8; ++ks) {
            const int k0 = ks * 32 + (l >> 4) * 8;
            float s, c; sincosf(dth * (float)k0, &s, &c);
            float sd, cd; sincosf(dth, &sd, &cd);
            short8 vh, vl;
            #pragma unroll
            for (int j = 0; j < 8; ++j) {
                float v = live ? ((par ? -s : c) * sc) : 0.f;
                unsigned ub = f2b(v);
                short h16 = (short)(ub >> 16);
                float rres = v - b2f(ub & 0xFFFF0000u);
                short l16 = (short)(f2b(rres) >> 16);
                vh[j] = h16; vl[j] = l16;
                float ncv = c * cd - s * sd, nsv = c * sd + s * cd;
                c = ncv; s = nsv;
            }
            Bh[u][ks] = vh; Bl[u][ks] = vl;
        }
    }

    const int i   = t & 31;
    const int slot = t >> 5;
    const int i15 = i & 15, imt = i >> 4;
    const int i15l = l & 15, ql = l >> 4;

    for (int ir = 0; ir < 8; ++ir) {
        const int row = blockIdx.x * 8 + ir;
        const int b = row >> 8, y = row & 255;
        __syncthreads();
        {
            const float* rp = x + (size_t)row * 8192;
            unsigned* al32 = (unsigned*)alds;
            #pragma unroll
            for (int c = 0; c < 16; ++c) {
                const int xp = slot + (c << 3);
                float v0 = rp[xp * 64 + i];
                float v1 = rp[xp * 64 + 32 + i];
                unsigned u0 = f2b(v0), u1 = f2b(v1);
                unsigned hi = (u0 >> 16) | (u1 & 0xFFFF0000u);
                float r0 = v0 - b2f(u0 & 0xFFFF0000u);
                float r1 = v1 - b2f(u1 & 0xFFFF0000u);
                unsigned lo = (f2b(r0) >> 16) | (f2b(r1) & 0xFFFF0000u);
                const int ks = xp >> 4, q = (xp & 15) >> 2, dw = xp & 3;
                const int base = (ks * 2 + imt) * 256 + (q * 16 + i15) * 4 + dw;
                al32[base] = hi;
                al32[base + 16 * 256] = lo;
            }
        }
        __syncthreads();
        floatx4 acc0 = {0.f, 0.f, 0.f, 0.f};
        floatx4 acc1 = {0.f, 0.f, 0.f, 0.f};
        #pragma unroll
        for (int ks = 0; ks < 8; ++ks) {
            const short8 ah = *(const short8*)(alds + ((ks * 2 + mt) * 512) + l * 8);
            const short8 al = *(const short8*)(alds + ((16 + ks * 2 + mt) * 512) + l * 8);
            acc0 = __builtin_amdgcn_mfma_f32_16x16x32_bf16(ah, Bh[0][ks], acc0, 0, 0, 0);
            acc0 = __builtin_amdgcn_mfma_f32_16x16x32_bf16(ah, Bl[0][ks], acc0, 0, 0, 0);
            acc0 = __builtin_amdgcn_mfma_f32_16x16x32_bf16(al, Bh[0][ks], acc0, 0, 0, 0);
            if (nn == 2) {
                acc1 = __builtin_amdgcn_mfma_f32_16x16x32_bf16(ah, Bh[1][ks], acc1, 0, 0, 0);
                acc1 = __builtin_amdgcn_mfma_f32_16x16x32_bf16(ah, Bl[1][ks], acc1, 0, 0, 0);
                acc1 = __builtin_amdgcn_mfma_f32_16x16x32_bf16(al, Bh[1][ks], acc1, 0, 0, 0);
            }
        }
        #pragma unroll
        for (int u = 0; u < 2; ++u) {
            if (u >= nn) break;
            const int nt = (g == 0) ? u : 2;
            const int n = nt * 16 + i15l;
            if (n < 34) {
                const int kwv = n >> 1, par = n & 1;
                float* dst = Xw + (((size_t)(b * 17 + kwv) * 256 + y) * 64) + par;
                const floatx4 a = (u == 0) ? acc0 : acc1;
                #pragma unroll
                for (int r = 0; r < 4; ++r) {
                    const int ii = mt * 16 + ql * 4 + r;
                    dst[ii * 2] = a[r];
                }
            }
        }
    }
}

// ---------------- KMID: fused fwd H-DFT + mode mix + inv H-DFT (unchanged) ----------------
__global__ __launch_bounds__(512) void kmid(const float2* __restrict__ Xw,
                                            const float2* __restrict__ wt,
                                            float2* __restrict__ T) {
    __shared__ __align__(16) float2 xsh[128 * 32];
    __shared__ __align__(16) float2 xhat[32 * 32];
    __shared__ __align__(16) float2 osl[32 * 32];
    const int t = threadIdx.x;
    const int bk = blockIdx.x;
    const int b = bk / 17, kw = bk - b * 17;
    const float4* src4 = (const float4*)(Xw + (size_t)bk * 8192);

    const int m1 = t & 31, ip2 = t >> 5;
    const int kh = (m1 < 16) ? m1 : m1 - 32;
    float wc, ws; sincosf(-TWO_PI * (float)kh * (1.f / 256.f), &ws, &wc);
    float tr = 1.f, ti = 0.f;
    float a0r = 0.f, a0i = 0.f, a1r = 0.f, a1i = 0.f;
    const float* xp = (const float*)xsh + ip2 * 4;
    for (int half = 0; half < 2; ++half) {
        __syncthreads();
        #pragma unroll
        for (int q = 0; q < 4; ++q) {
            int v = q * 512 + t;
            ((float4*)xsh)[v] = src4[half * 2048 + v];
        }
        __syncthreads();
        #pragma unroll 8
        for (int yy = 0; yy < 128; ++yy) {
            float4 v = *(const float4*)(xp + yy * 64);
            a0r = fmaf(v.x, tr, a0r); a0r = fmaf(-v.y, ti, a0r);
            a0i = fmaf(v.x, ti, a0i); a0i = fmaf(v.y, tr, a0i);
            a1r = fmaf(v.z, tr, a1r); a1r = fmaf(-v.w, ti, a1r);
            a1i = fmaf(v.z, ti, a1i); a1i = fmaf(v.w, tr, a1i);
            cmul_upd(tr, ti, wc, ws);
        }
    }
    *(float4*)(xhat + m1 * 32 + ip2 * 2) = make_float4(a0r, a0i, a1r, a1i);
    __syncthreads();

    {
        const int o2 = t & 15, m = t >> 4;
        const float4* wp = (const float4*)wt + ((size_t)(kw * 32 + m) * 32) * 16 + o2;
        float ar0 = 0.f, ai0 = 0.f, ar1 = 0.f, ai1 = 0.f;
        #pragma unroll 8
        for (int ii = 0; ii < 32; ++ii) {
            float2 xv = xhat[m * 32 + ii];
            float4 wv = wp[(size_t)ii * 16];
            ar0 = fmaf(xv.x, wv.x, ar0); ar0 = fmaf(-xv.y, wv.y, ar0);
            ai0 = fmaf(xv.x, wv.y, ai0); ai0 = fmaf(xv.y, wv.x, ai0);
            ar1 = fmaf(xv.x, wv.z, ar1); ar1 = fmaf(-xv.y, wv.w, ar1);
            ai1 = fmaf(xv.x, wv.w, ai1); ai1 = fmaf(xv.y, wv.z, ai1);
        }
        *(float4*)(osl + m * 32 + o2 * 2) = make_float4(ar0, ai0, ar1, ai1);
    }
    __syncthreads();

    {
        const int y = t & 255, oh = t >> 8;
        float uc, us; sincosf(TWO_PI * (float)y * (1.f / 256.f), &us, &uc);
        float tr2 = 1.f, ti2 = 0.f;
        float ar[16], ai[16];
        #pragma unroll
        for (int o = 0; o < 16; ++o) { ar[o] = 0.f; ai[o] = 0.f; }
        for (int m = 0; m < 32; ++m) {
            if (m == 16) ti2 = -ti2;
            #pragma unroll
            for (int o2 = 0; o2 < 8; ++o2) {
                float4 v = *(const float4*)((const float*)osl + m * 64 + oh * 32 + o2 * 4);
                int o = o2 * 2;
                ar[o]   = fmaf(v.x, tr2, ar[o]);   ar[o]   = fmaf(-v.y, ti2, ar[o]);
                ai[o]   = fmaf(v.x, ti2, ai[o]);   ai[o]   = fmaf(v.y, tr2, ai[o]);
                ar[o+1] = fmaf(v.z, tr2, ar[o+1]); ar[o+1] = fmaf(-v.w, ti2, ar[o+1]);
                ai[o+1] = fmaf(v.z, ti2, ai[o+1]); ai[o+1] = fmaf(v.w, tr2, ai[o+1]);
            }
            cmul_upd(tr2, ti2, uc, us);
        }
        float2* dst = T + ((size_t)(b * 256 + y) * 17 + kw) * 32 + oh * 16;
        #pragma unroll
        for (int o2 = 0; o2 < 8; ++o2)
            *(float4*)(dst + o2 * 2) =
                make_float4(ar[o2*2], ai[o2*2], ar[o2*2+1], ai[o2*2+1]);
    }
}

// ---------------- K5: inverse-W reconstruction via MFMA + bias ----------------
// Per (b,y): D[x=256][o=32] = sum_{k<34} A[x][k] * Tslab[k][o],  out = D + bias
// Tslab[2kw+reim][o] = Tfloat[kw*64 + o*2 + reim]. A from precomputed Atab (bf16 hi/lo).
// 3-MFMA split (ah*bh + ah*bl + al*bh). Grid 4096 blocks (one per (b,y)).
__global__ __launch_bounds__(256) void k5_mfma(const float2* __restrict__ T,
                                               const short8* __restrict__ Atab,
                                               const float* __restrict__ bias,
                                               float* __restrict__ out) {
    __shared__ __align__(16) float trl[1088];        // raw T slab (floats)
    __shared__ __align__(16) short bfr[8192];        // B frags [nt][ks][h][lane][8]
    __shared__ float bl[32];
    const int t = threadIdx.x;
    const int blk = blockIdx.x;                      // b*256 + y
    {
        const float4* src4 = (const float4*)(T + (size_t)blk * 544);
        ((float4*)trl)[t] = src4[t];
        if (t < 16) ((float4*)trl)[256 + t] = src4[256 + t];
        if (t < 32) bl[t] = bias[t];
    }
    __syncthreads();
    // convert slab -> B fragments (thread t = one (nt, ks, lane); 8 k-elems)
    {
        const int nt = t >> 7, ks = (t >> 6) & 1, lc = t & 63;
        const int o = nt * 16 + (lc & 15);
        const int kbase = ks * 32 + (lc >> 4) * 8;
        short8 vh, vl;
        #pragma unroll
        for (int j = 0; j < 8; ++j) {
            const int k = kbase + j;
            float v = (k < 34) ? trl[(k >> 1) * 64 + o * 2 + (k & 1)] : 0.f;
            unsigned ub = f2b(v);
            vh[j] = (short)(ub >> 16);
            float r = v - b2f(ub & 0xFFFF0000u);
            vl[j] = (short)(f2b(r) >> 16);
        }
        short8* bp = (short8*)bfr;
        bp[((nt * 2 + ks) * 2 + 0) * 64 + lc] = vh;
        bp[((nt * 2 + ks) * 2 + 1) * 64 + lc] = vl;
    }
    __syncthreads();
    const int w = t >> 6, l = t & 63;
    const short8* bp = (const short8*)bfr;
    short8 B[2][2][2];                               // [nt][ks][h]
    #pragma unroll
    for (int nt = 0; nt < 2; ++nt)
        #pragma unroll
        for (int ks = 0; ks < 2; ++ks) {
            B[nt][ks][0] = bp[((nt * 2 + ks) * 2 + 0) * 64 + l];
            B[nt][ks][1] = bp[((nt * 2 + ks) * 2 + 1) * 64 + l];
        }
    floatx4 acc[4][2];
    #pragma unroll
    for (int mtp = 0; mtp < 4; ++mtp) {
        acc[mtp][0] = (floatx4){0.f, 0.f, 0.f, 0.f};
        acc[mtp][1] = (floatx4){0.f, 0.f, 0.f, 0.f};
    }
    #pragma unroll
    for (int mtp = 0; mtp < 4; ++mtp) {
        const int mt = w * 4 + mtp;
        #pragma unroll
        for (int ks = 0; ks < 2; ++ks) {
            const short8 ah = Atab[((mt * 2 + ks) * 2 + 0) * 64 + l];
            const short8 al = Atab[((mt * 2 + ks) * 2 + 1) * 64 + l];
            #pragma unroll
            for (int nt = 0; nt < 2; ++nt) {
                acc[mtp][nt] = __builtin_amdgcn_mfma_f32_16x16x32_bf16(ah, B[nt][ks][0], acc[mtp][nt], 0, 0, 0);
                acc[mtp][nt] = __builtin_amdgcn_mfma_f32_16x16x32_bf16(ah, B[nt][ks][1], acc[mtp][nt], 0, 0, 0);
                acc[mtp][nt] = __builtin_amdgcn_mfma_f32_16x16x32_bf16(al, B[nt][ks][0], acc[mtp][nt], 0, 0, 0);
            }
        }
    }
    // epilogue: D lane l reg r -> (x = mt*16 + (l>>4)*4 + r, o = nt*16 + (l&15))
    float* orow = out + (size_t)blk * 8192;
    const int ql = l >> 4, i15 = l & 15;
    #pragma unroll
    for (int nt = 0; nt < 2; ++nt) {
        const float bb = bl[nt * 16 + i15];
        #pragma unroll
        for (int mtp = 0; mtp < 4; ++mtp) {
            const int xbase = (w * 4 + mtp) * 16 + ql * 4;
            #pragma unroll
            for (int r = 0; r < 4; ++r)
                orow[(size_t)(xbase + r) * 32 + nt * 16 + i15] = acc[mtp][nt][r] + bb;
        }
    }
}

extern "C" void kernel_launch(void* const* d_in, const int* in_sizes, int n_in,
                              void* d_out, int out_size, void* d_ws, size_t ws_size,
                              hipStream_t stream) {
    const float* x    = (const float*)d_in[0];
    const float* w1r  = (const float*)d_in[1];
    const float* w1i  = (const float*)d_in[2];
    const float* w2r  = (const float*)d_in[3];
    const float* w2i  = (const float*)d_in[4];
    const float* bias = (const float*)d_in[5];
    float* out = (float*)d_out;

    char* ws = (char*)d_ws;
    // Xw: 17,825,792 B | T: 17,825,792 B | wt: 4,456,448 B | Atab: 65,536 B
    float2* Xw   = (float2*)ws;
    float2* T    = (float2*)(ws + 17825792);
    float2* wt   = (float2*)(ws + 2 * 17825792);
    short8* Atab = (short8*)(ws + 2 * 17825792 + 4456448);

    k5pre<<<8, 256, 0, stream>>>(Atab);
    k0_wt<<<128, 256, 0, stream>>>(w1r, w1i, w2r, w2i, wt);
    k1_fwdW_mfma<<<512, 256, 0, stream>>>(x, (float*)Xw);
    kmid<<<NB * EM1, 512, 0, stream>>>(Xw, wt, T);
    k5_mfma<<<NB * NH, 256, 0, stream>>>(T, Atab, bias, out);
}